// Round 7
// baseline (185.415 us; speedup 1.0000x reference)
//
#include <hip/hip_runtime.h>
#include <hip/hip_bf16.h>

// Problem dims (fixed by setup_inputs)
#define NODES 8192
#define DIM   200
#define NEDGE 4096
#define DEGREE 16
#define NB    4
#define NNODE 2048   // nodes per graph = NODES/NB
#define HD    128
#define MT    8      // row tile (8 rows/block -> 1024 blocks -> 4 wg/CU)

// ---- k_front: colsum (blocks 0..255) + edge count/dedupe (256..271)
// ----          + Wg = W@gnn_w rows (272..371) + bg (372) + text path (373..376)
__global__ void k_front(const float* __restrict__ x, const int* __restrict__ en,
                        const float* __restrict__ W, const float* __restrict__ gnn_w,
                        const float* __restrict__ bias, const float* __restrict__ gnn_b,
                        const float* __restrict__ text, const float* __restrict__ text_w,
                        const float* __restrict__ text_b, const float* __restrict__ in_w,
                        const float* __restrict__ in_b, const float* __restrict__ aow,
                        const float* __restrict__ aob, const float* __restrict__ fgw,
                        const float* __restrict__ fgb, float* __restrict__ colsum,
                        int* __restrict__ cnt, int* __restrict__ emask,
                        float* __restrict__ Wg, float* __restrict__ bg,
                        float* __restrict__ attO, float* __restrict__ attg) {
    __shared__ float st[DIM];
    __shared__ float part[2][HD];
    __shared__ float vin[HD];
    int b = blockIdx.x, t = threadIdx.x;
    if (b < 256) {                       // coalesced column-sum, 32 rows/block
        if (t < DIM) {
            float acc = 0.f;
            int r0 = b * 32;
            for (int r = 0; r < 32; r++) acc += x[(r0 + r) * DIM + t];
            atomicAdd(&colsum[t], acc);
        }
        return;
    }
    if (b < 272) {                       // per-edge dedupe (set semantics) + counts
        int e = (b - 256) * 256 + t;     // 16*256 == NEDGE exactly
        int idx[DEGREE];
#pragma unroll
        for (int i = 0; i < DEGREE; i++) idx[i] = en[e * DEGREE + i];
        int mask = 0;
#pragma unroll
        for (int i = 0; i < DEGREE; i++) {
            bool uniq = true;
            for (int j = 0; j < i; j++) uniq = uniq && (idx[j] != idx[i]);
            if (uniq) { mask |= (1 << i); atomicAdd(&cnt[idx[i]], 1); }
        }
        emask[e] = mask;
        return;
    }
    if (b < 372) {                       // Wg rows, 2 rows per block
        int r = 2 * (b - 272) + (t >> 7);
        int c = t & 127;
        const float* vec = &W[r * DIM];
        float acc = 0.f;
        for (int k = 0; k < DIM; k++) acc += vec[k] * gnn_w[k * HD + c];
        Wg[r * HD + c] = acc;
        return;
    }
    if (b == 372) {                      // bg = bias @ gnn_w + gnn_b
        if (t < HD) {
            float acc = 0.f;
            for (int k = 0; k < DIM; k++) acc += bias[k] * gnn_w[k * HD + t];
            bg[t] = acc + gnn_b[t];
        }
        return;
    }
    // b in [373,377): text path for graph g, k-parallel GEMV chain.
    // q/k/softmax dead (kv_len==1 -> softmax==1 -> att = v broadcast).
    int g = b - 373;
    int c = t & 127, h = t >> 7;
    if (t < DIM) st[t] = text[g * DIM + t];
    __syncthreads();
    // tp = text @ text_w + text_b   (k=200, split 100/100)
    {
        float acc = 0.f;
        int k0 = h * 100;
        for (int k = k0; k < k0 + 100; k++) acc += st[k] * text_w[k * HD + c];
        part[h][c] = acc;
    }
    __syncthreads();
    if (t < HD) vin[t] = part[0][t] + part[1][t] + text_b[t];
    __syncthreads();
    // v = tp @ in_w[:, 2H:3H] + in_b[2H:3H]   (k=128, split 64/64)
    {
        float acc = 0.f;
        int k0 = h * 64;
        for (int k = k0; k < k0 + 64; k++) acc += vin[k] * in_w[k * 3 * HD + 2 * HD + c];
        part[h][c] = acc;
    }
    __syncthreads();
    if (t < HD) vin[t] = part[0][t] + part[1][t] + in_b[2 * HD + t];
    __syncthreads();
    // attO = v @ aow + aob
    {
        float acc = 0.f;
        int k0 = h * 64;
        for (int k = k0; k < k0 + 64; k++) acc += vin[k] * aow[k * HD + c];
        part[h][c] = acc;
    }
    __syncthreads();
    if (t < HD) {
        float ao = part[0][t] + part[1][t] + aob[t];
        attO[g * HD + t] = ao;
        vin[t] = ao;
    }
    __syncthreads();
    // attg = attO @ fgw[H:2H, :] + fgb
    {
        float acc = 0.f;
        int k0 = h * 64;
        for (int k = k0; k < k0 + 64; k++) acc += vin[k] * fgw[(HD + k) * HD + c];
        part[h][c] = acc;
    }
    __syncthreads();
    if (t < HD) attg[g * HD + t] = part[0][t] + part[1][t] + fgb[t];
}

// ---- k_xwg: blocks 0..1023 = out2 = x@Wg (8-row tiles);
// ----        block 1024 = alpha; blocks 1025..1056 = dv from cnt ----
__global__ void k_xwg(const float* __restrict__ x, const float* __restrict__ Wg,
                      float* __restrict__ out2, const float* __restrict__ colsum,
                      const float* __restrict__ gate_w, const float* __restrict__ gate_b,
                      float* __restrict__ alpha, const int* __restrict__ cnt,
                      float* __restrict__ dv) {
    __shared__ float sx[MT * DIM];
    int t = threadIdx.x;
    if (blockIdx.x == NODES / MT) {      // alpha = sigmoid(mean(x)@gate_w + gate_b)
        __shared__ float red[256];
        red[t] = (t < DIM) ? colsum[t] * gate_w[t] : 0.f;
        __syncthreads();
        for (int o = 128; o > 0; o >>= 1) {
            if (t < o) red[t] += red[t + o];
            __syncthreads();
        }
        if (t == 0) {
            float z = red[0] / (float)NODES + gate_b[0];
            alpha[0] = 1.0f / (1.0f + expf(-z));
        }
        return;
    }
    if (blockIdx.x > NODES / MT) {       // dv = 1/sqrt(cnt/16 + eps)
        int n = (blockIdx.x - NODES / MT - 1) * 256 + t;
        dv[n] = 1.0f / sqrtf((float)cnt[n] * (1.0f / 16.0f) + 1e-8f);
        return;
    }
    int bm = blockIdx.x * MT;
    const float4* x4 = (const float4*)(x + bm * DIM);
    float4* sx4 = (float4*)sx;
    for (int i = t; i < MT * DIM / 4; i += 256) sx4[i] = x4[i];
    __syncthreads();
    int c = t & 127, rg = t >> 7;        // 2 row-groups x 128 cols, 4 rows each
    float acc[4] = {0.f, 0.f, 0.f, 0.f};
    for (int k = 0; k < DIM; k++) {
        float w = Wg[k * HD + c];
#pragma unroll
        for (int i = 0; i < 4; i++) acc[i] += sx[(rg * 4 + i) * DIM + k] * w;
    }
#pragma unroll
    for (int i = 0; i < 4; i++) out2[(bm + rg * 4 + i) * HD + c] = acc[i];
}

// ---- k_edge: tE = de * sum_{i in uniq(e)} dv*out2; atomically scatter to accum ----
__global__ void k_edge(const int* __restrict__ en, const int* __restrict__ emask,
                       const float* __restrict__ dv, const float* __restrict__ out2,
                       float* __restrict__ accum) {
    int e = blockIdx.x * 2 + (threadIdx.x >> 7);
    int c = threadIdx.x & 127;
    int m = emask[e];
    float De = (float)__popc(m) * (1.0f / 16.0f);
    float de = 1.0f / (De + 1e-8f);
    int nd[DEGREE];
#pragma unroll
    for (int i = 0; i < DEGREE; i++) nd[i] = en[e * DEGREE + i];
    float acc = 0.f;
#pragma unroll
    for (int i = 0; i < DEGREE; i++)
        if ((m >> i) & 1) acc += dv[nd[i]] * out2[nd[i] * HD + c];
    float s = de * acc;
#pragma unroll
    for (int i = 0; i < DEGREE; i++)
        if ((m >> i) & 1) atomicAdd(&accum[nd[i] * HD + c], s);
}

// ---- fused tail, 8-row tiles (1024 blocks):
// gp = a*out2 + (1-a)*dv/256*accum + bg -> gate -> fused -> out = fused@opw+opb
__global__ void k_tail(const float* __restrict__ out2, const float* __restrict__ accum,
                       const float* __restrict__ dv, const float* __restrict__ alpha,
                       const float* __restrict__ bg, const float* __restrict__ fgw,
                       const float* __restrict__ attO, const float* __restrict__ attg,
                       const float* __restrict__ opw, const float* __restrict__ opb,
                       float* __restrict__ out) {
    __shared__ float sgp[MT][HD];
    int bm = blockIdx.x * MT;
    int b = bm >> 11;                    // graph id (NNODE=2048, tiles don't straddle)
    int t = threadIdx.x;
    int c = t & 127, rg = t >> 7;
    float a = alpha[0];
    float bgc = bg[c];
    // phase 1: gp rows into LDS (all loads coalesced now)
#pragma unroll
    for (int i = 0; i < 4; i++) {
        int r = rg * 4 + i;
        int n = bm + r;
        float hyp = accum[n * HD + c] * dv[n] * (1.0f / 256.0f);
        sgp[r][c] = a * out2[n * HD + c] + (1.0f - a) * hyp + bgc;
    }
    __syncthreads();
    // phase 2: gate logits (weight element reused across 4 rows)
    float ao = attO[b * HD + c];
    float ag = attg[b * HD + c];
    float acc[4] = {ag, ag, ag, ag};
    for (int j = 0; j < HD; j++) {
        float w = fgw[j * HD + c];
#pragma unroll
        for (int i = 0; i < 4; i++) acc[i] += sgp[rg * 4 + i][j] * w;
    }
    __syncthreads();
    // phase 3: fused = g*gp + (1-g)*attO, in place
#pragma unroll
    for (int i = 0; i < 4; i++) {
        int r = rg * 4 + i;
        float g = 1.0f / (1.0f + expf(-acc[i]));
        sgp[r][c] = g * sgp[r][c] + (1.0f - g) * ao;
    }
    __syncthreads();
    // phase 4: out = fused @ opw + opb (threads 0..199 own one output col)
    if (t < DIM) {
        float accO[MT];
        float ob = opb[t];
#pragma unroll
        for (int i = 0; i < MT; i++) accO[i] = ob;
        for (int j = 0; j < HD; j++) {
            float w = opw[j * DIM + t];
#pragma unroll
            for (int i = 0; i < MT; i++) accO[i] += sgp[i][j] * w;
        }
#pragma unroll
        for (int i = 0; i < MT; i++) out[(bm + i) * DIM + t] = accO[i];
    }
}

extern "C" void kernel_launch(void* const* d_in, const int* in_sizes, int n_in,
                              void* d_out, int out_size, void* d_ws, size_t ws_size,
                              hipStream_t stream) {
    const float* x      = (const float*)d_in[0];
    const float* text   = (const float*)d_in[1];
    const float* W      = (const float*)d_in[2];
    const float* bias   = (const float*)d_in[3];
    const float* gate_w = (const float*)d_in[4];
    const float* gate_b = (const float*)d_in[5];
    const float* gnn_w  = (const float*)d_in[6];
    const float* gnn_b  = (const float*)d_in[7];
    const float* text_w = (const float*)d_in[8];
    const float* text_b = (const float*)d_in[9];
    const float* in_w   = (const float*)d_in[10];
    const float* in_b   = (const float*)d_in[11];
    const float* aow    = (const float*)d_in[12];
    const float* aob    = (const float*)d_in[13];
    const float* fgw    = (const float*)d_in[14];
    const float* fgb    = (const float*)d_in[15];
    const float* opw    = (const float*)d_in[16];
    const float* opb    = (const float*)d_in[17];
    const int*   en     = (const int*)d_in[18];
    float* out = (float*)d_out;

    // Scratch layout (~8.4 MB; ws_size is 256 MB per the harness poison fill).
    // cnt + colsum + accum contiguous -> one memset covers all three.
    char* p = (char*)d_ws;
    int*   cnt    = (int*)p;   p += NODES * sizeof(int);
    float* colsum = (float*)p; p += DIM * sizeof(float);
    float* accum  = (float*)p; p += (size_t)NODES * HD * sizeof(float);   // 4 MB
    float* out2   = (float*)p; p += (size_t)NODES * HD * sizeof(float);   // 4 MB
    float* Wg     = (float*)p; p += DIM * HD * sizeof(float);
    float* dv     = (float*)p; p += NODES * sizeof(float);
    float* alpha  = (float*)p; p += sizeof(float);
    float* bg     = (float*)p; p += HD * sizeof(float);
    float* attO   = (float*)p; p += NB * HD * sizeof(float);
    float* attg   = (float*)p; p += NB * HD * sizeof(float);
    int*   emask  = (int*)p;   p += NEDGE * sizeof(int);

    hipMemsetAsync(cnt, 0, (NODES + DIM + NODES * HD) * sizeof(int), stream);

    k_front<<<377, 256, 0, stream>>>(x, en, W, gnn_w, bias, gnn_b, text, text_w,
                                     text_b, in_w, in_b, aow, aob, fgw, fgb,
                                     colsum, cnt, emask, Wg, bg, attO, attg);
    k_xwg<<<NODES / MT + 1 + NODES / 256, 256, 0, stream>>>(x, Wg, out2, colsum, gate_w,
                                                            gate_b, alpha, cnt, dv);
    k_edge<<<NEDGE / 2, 256, 0, stream>>>(en, emask, dv, out2, accum);
    k_tail<<<NODES / MT, 256, 0, stream>>>(out2, accum, dv, alpha, bg, fgw,
                                           attO, attg, opw, opb, out);
}

// Round 8
// 167.641 us; speedup vs baseline: 1.1060x; 1.1060x over previous
//
#include <hip/hip_runtime.h>
#include <hip/hip_bf16.h>

// Problem dims (fixed by setup_inputs)
#define NODES 8192
#define DIM   200
#define NEDGE 4096
#define DEGREE 16
#define NB    4
#define NNODE 2048   // nodes per graph = NODES/NB
#define HD    128
#define MT    8      // row tile (8 rows/block -> 1024 blocks -> 4 wg/CU)
#define ECAP  32     // fixed stride of per-node edge list (Poisson(8); P(>32)~1e-11/node)

__device__ __forceinline__ float dv_of(int cnt) {
    return 1.0f / sqrtf((float)cnt * (1.0f / 16.0f) + 1e-8f);
}

// ---- k_front: colsum (blocks 0..255) + edge dedupe/count/list-fill (256..271)
// ----          + Wg = W@gnn_w rows (272..371) + bg (372) + text path (373..376)
__global__ void k_front(const float* __restrict__ x, const int* __restrict__ en,
                        const float* __restrict__ W, const float* __restrict__ gnn_w,
                        const float* __restrict__ bias, const float* __restrict__ gnn_b,
                        const float* __restrict__ text, const float* __restrict__ text_w,
                        const float* __restrict__ text_b, const float* __restrict__ in_w,
                        const float* __restrict__ in_b, const float* __restrict__ aow,
                        const float* __restrict__ aob, const float* __restrict__ fgw,
                        const float* __restrict__ fgb, float* __restrict__ colsum,
                        int* __restrict__ cnt, int* __restrict__ emask,
                        int* __restrict__ elist2, float* __restrict__ Wg,
                        float* __restrict__ bg, float* __restrict__ attO,
                        float* __restrict__ attg) {
    __shared__ float st[DIM];
    __shared__ float part[2][HD];
    __shared__ float vin[HD];
    int b = blockIdx.x, t = threadIdx.x;
    if (b < 256) {                       // coalesced column-sum, 32 rows/block
        if (t < DIM) {
            float acc = 0.f;
            int r0 = b * 32;
            for (int r = 0; r < 32; r++) acc += x[(r0 + r) * DIM + t];
            atomicAdd(&colsum[t], acc);
        }
        return;
    }
    if (b < 272) {                       // per-edge dedupe (set semantics) + counts
        int e = (b - 256) * 256 + t;     // 16*256 == NEDGE exactly
        int idx[DEGREE];
#pragma unroll
        for (int i = 0; i < DEGREE; i++) idx[i] = en[e * DEGREE + i];
        int mask = 0;
#pragma unroll
        for (int i = 0; i < DEGREE; i++) {
            bool uniq = true;
            for (int j = 0; j < i; j++) uniq = uniq && (idx[j] != idx[i]);
            if (uniq) {
                mask |= (1 << i);
                int slot = atomicAdd(&cnt[idx[i]], 1);   // slot doubles as list index
                if (slot < ECAP) elist2[idx[i] * ECAP + slot] = e;
            }
        }
        emask[e] = mask;
        return;
    }
    if (b < 372) {                       // Wg rows, 2 rows per block
        int r = 2 * (b - 272) + (t >> 7);
        int c = t & 127;
        const float* vec = &W[r * DIM];
        float acc = 0.f;
        for (int k = 0; k < DIM; k++) acc += vec[k] * gnn_w[k * HD + c];
        Wg[r * HD + c] = acc;
        return;
    }
    if (b == 372) {                      // bg = bias @ gnn_w + gnn_b
        if (t < HD) {
            float acc = 0.f;
            for (int k = 0; k < DIM; k++) acc += bias[k] * gnn_w[k * HD + t];
            bg[t] = acc + gnn_b[t];
        }
        return;
    }
    // b in [373,377): text path for graph g, k-parallel GEMV chain.
    // q/k/softmax dead (kv_len==1 -> softmax==1 -> att = v broadcast).
    int g = b - 373;
    int c = t & 127, h = t >> 7;
    if (t < DIM) st[t] = text[g * DIM + t];
    __syncthreads();
    {   // tp = text @ text_w + text_b   (k=200, split 100/100)
        float acc = 0.f;
        int k0 = h * 100;
        for (int k = k0; k < k0 + 100; k++) acc += st[k] * text_w[k * HD + c];
        part[h][c] = acc;
    }
    __syncthreads();
    if (t < HD) vin[t] = part[0][t] + part[1][t] + text_b[t];
    __syncthreads();
    {   // v = tp @ in_w[:, 2H:3H] + in_b[2H:3H]   (k=128, split 64/64)
        float acc = 0.f;
        int k0 = h * 64;
        for (int k = k0; k < k0 + 64; k++) acc += vin[k] * in_w[k * 3 * HD + 2 * HD + c];
        part[h][c] = acc;
    }
    __syncthreads();
    if (t < HD) vin[t] = part[0][t] + part[1][t] + in_b[2 * HD + t];
    __syncthreads();
    {   // attO = v @ aow + aob
        float acc = 0.f;
        int k0 = h * 64;
        for (int k = k0; k < k0 + 64; k++) acc += vin[k] * aow[k * HD + c];
        part[h][c] = acc;
    }
    __syncthreads();
    if (t < HD) {
        float ao = part[0][t] + part[1][t] + aob[t];
        attO[g * HD + t] = ao;
        vin[t] = ao;
    }
    __syncthreads();
    {   // attg = attO @ fgw[H:2H, :] + fgb
        float acc = 0.f;
        int k0 = h * 64;
        for (int k = k0; k < k0 + 64; k++) acc += vin[k] * fgw[(HD + k) * HD + c];
        part[h][c] = acc;
    }
    __syncthreads();
    if (t < HD) attg[g * HD + t] = part[0][t] + part[1][t] + fgb[t];
}

// ---- k_xwg: blocks 0..1023 = out2 = x@Wg (8-row tiles); block 1024 = alpha ----
__global__ void k_xwg(const float* __restrict__ x, const float* __restrict__ Wg,
                      float* __restrict__ out2, const float* __restrict__ colsum,
                      const float* __restrict__ gate_w, const float* __restrict__ gate_b,
                      float* __restrict__ alpha) {
    __shared__ float sx[MT * DIM];
    int t = threadIdx.x;
    if (blockIdx.x == NODES / MT) {      // alpha = sigmoid(mean(x)@gate_w + gate_b)
        __shared__ float red[256];
        red[t] = (t < DIM) ? colsum[t] * gate_w[t] : 0.f;
        __syncthreads();
        for (int o = 128; o > 0; o >>= 1) {
            if (t < o) red[t] += red[t + o];
            __syncthreads();
        }
        if (t == 0) {
            float z = red[0] / (float)NODES + gate_b[0];
            alpha[0] = 1.0f / (1.0f + expf(-z));
        }
        return;
    }
    int bm = blockIdx.x * MT;
    const float4* x4 = (const float4*)(x + bm * DIM);
    float4* sx4 = (float4*)sx;
    for (int i = t; i < MT * DIM / 4; i += 256) sx4[i] = x4[i];
    __syncthreads();
    int c = t & 127, rg = t >> 7;        // 2 row-groups x 128 cols, 4 rows each
    float acc[4] = {0.f, 0.f, 0.f, 0.f};
    for (int k = 0; k < DIM; k++) {
        float w = Wg[k * HD + c];
#pragma unroll
        for (int i = 0; i < 4; i++) acc[i] += sx[(rg * 4 + i) * DIM + k] * w;
    }
#pragma unroll
    for (int i = 0; i < 4; i++) out2[(bm + rg * 4 + i) * HD + c] = acc[i];
}

// ---- tE[e,:] = de[e] * sum_{i in uniq(e)} dv[m_i] * out2[m_i,:] ----
__global__ void k_tE(const int* __restrict__ en, const int* __restrict__ emask,
                     const int* __restrict__ cnt, const float* __restrict__ out2,
                     float* __restrict__ tE) {
    int e = blockIdx.x * 2 + (threadIdx.x >> 7);
    int c = threadIdx.x & 127;
    int m = emask[e];
    float De = (float)__popc(m) * (1.0f / 16.0f);
    float de = 1.0f / (De + 1e-8f);
    int nd[DEGREE];
#pragma unroll
    for (int i = 0; i < DEGREE; i++) nd[i] = en[e * DEGREE + i];
    float acc = 0.f;
#pragma unroll
    for (int i = 0; i < DEGREE; i++)
        if ((m >> i) & 1) acc += dv_of(cnt[nd[i]]) * out2[nd[i] * HD + c];
    tE[e * HD + c] = de * acc;
}

// ---- fused tail, 8-row tiles (1024 blocks):
// elist2 gather -> gp -> gate -> fused -> out = fused@opw + opb
__global__ void k_tail(const float* __restrict__ out2, const float* __restrict__ tE,
                       const int* __restrict__ cnt, const int* __restrict__ elist2,
                       const float* __restrict__ alpha, const float* __restrict__ bg,
                       const float* __restrict__ fgw, const float* __restrict__ attO,
                       const float* __restrict__ attg, const float* __restrict__ opw,
                       const float* __restrict__ opb, float* __restrict__ out) {
    __shared__ float sgp[MT][HD];
    __shared__ int   sid[MT][ECAP];
    __shared__ int   scount[MT];
    int bm = blockIdx.x * MT;
    int b = bm >> 11;                    // graph id (NNODE=2048, tiles don't straddle)
    int t = threadIdx.x;
    // phase 0: stage per-row edge lists into LDS (32 threads per row, 1 load each)
    {
        int r = t >> 5, sl = t & 31;
        int n = bm + r;
        int cc = cnt[n]; cc = cc < ECAP ? cc : ECAP;
        if (sl == 0) scount[r] = cc;
        if (sl < cc) sid[r][sl] = elist2[n * ECAP + sl];
    }
    __syncthreads();
    int c = t & 127, rg = t >> 7;
    float a = alpha[0];
    float bgc = bg[c];
    // phase 1: gp rows into LDS (edge ids from LDS -> independent tE loads)
#pragma unroll
    for (int i = 0; i < 4; i++) {
        int r = rg * 4 + i;
        int n = bm + r;
        int cc = scount[r];
        float hyp = 0.f;
        for (int j = 0; j < cc; j++) hyp += tE[sid[r][j] * HD + c];
        hyp *= dv_of(cnt[n]) * (1.0f / 256.0f);
        sgp[r][c] = a * out2[n * HD + c] + (1.0f - a) * hyp + bgc;
    }
    __syncthreads();
    // phase 2: gate logits (weight element reused across 4 rows)
    float ao = attO[b * HD + c];
    float ag = attg[b * HD + c];
    float acc[4] = {ag, ag, ag, ag};
    for (int j = 0; j < HD; j++) {
        float w = fgw[j * HD + c];
#pragma unroll
        for (int i = 0; i < 4; i++) acc[i] += sgp[rg * 4 + i][j] * w;
    }
    __syncthreads();
    // phase 3: fused = g*gp + (1-g)*attO, in place
#pragma unroll
    for (int i = 0; i < 4; i++) {
        int r = rg * 4 + i;
        float g = 1.0f / (1.0f + expf(-acc[i]));
        sgp[r][c] = g * sgp[r][c] + (1.0f - g) * ao;
    }
    __syncthreads();
    // phase 4: out = fused @ opw + opb (threads 0..199 own one output col)
    if (t < DIM) {
        float accO[MT];
        float ob = opb[t];
#pragma unroll
        for (int i = 0; i < MT; i++) accO[i] = ob;
        for (int j = 0; j < HD; j++) {
            float w = opw[j * DIM + t];
#pragma unroll
            for (int i = 0; i < MT; i++) accO[i] += sgp[i][j] * w;
        }
#pragma unroll
        for (int i = 0; i < MT; i++) out[(bm + i) * DIM + t] = accO[i];
    }
}

extern "C" void kernel_launch(void* const* d_in, const int* in_sizes, int n_in,
                              void* d_out, int out_size, void* d_ws, size_t ws_size,
                              hipStream_t stream) {
    const float* x      = (const float*)d_in[0];
    const float* text   = (const float*)d_in[1];
    const float* W      = (const float*)d_in[2];
    const float* bias   = (const float*)d_in[3];
    const float* gate_w = (const float*)d_in[4];
    const float* gate_b = (const float*)d_in[5];
    const float* gnn_w  = (const float*)d_in[6];
    const float* gnn_b  = (const float*)d_in[7];
    const float* text_w = (const float*)d_in[8];
    const float* text_b = (const float*)d_in[9];
    const float* in_w   = (const float*)d_in[10];
    const float* in_b   = (const float*)d_in[11];
    const float* aow    = (const float*)d_in[12];
    const float* aob    = (const float*)d_in[13];
    const float* fgw    = (const float*)d_in[14];
    const float* fgb    = (const float*)d_in[15];
    const float* opw    = (const float*)d_in[16];
    const float* opb    = (const float*)d_in[17];
    const int*   en     = (const int*)d_in[18];
    float* out = (float*)d_out;

    // Scratch layout (~8 MB of the 256 MB d_ws). cnt+colsum contiguous -> one memset.
    char* p = (char*)d_ws;
    int*   cnt    = (int*)p;   p += NODES * sizeof(int);
    float* colsum = (float*)p; p += DIM * sizeof(float);
    float* out2   = (float*)p; p += (size_t)NODES * HD * sizeof(float);   // 4 MB
    float* tE     = (float*)p; p += (size_t)NEDGE * HD * sizeof(float);   // 2 MB
    int*   elist2 = (int*)p;   p += (size_t)NODES * ECAP * sizeof(int);   // 1 MB
    float* Wg     = (float*)p; p += DIM * HD * sizeof(float);
    float* alpha  = (float*)p; p += sizeof(float);
    float* bg     = (float*)p; p += HD * sizeof(float);
    float* attO   = (float*)p; p += NB * HD * sizeof(float);
    float* attg   = (float*)p; p += NB * HD * sizeof(float);
    int*   emask  = (int*)p;   p += NEDGE * sizeof(int);

    hipMemsetAsync(cnt, 0, (NODES + DIM) * sizeof(int), stream);

    k_front<<<377, 256, 0, stream>>>(x, en, W, gnn_w, bias, gnn_b, text, text_w,
                                     text_b, in_w, in_b, aow, aob, fgw, fgb,
                                     colsum, cnt, emask, elist2, Wg, bg, attO, attg);
    k_xwg<<<NODES / MT + 1, 256, 0, stream>>>(x, Wg, out2, colsum, gate_w, gate_b, alpha);
    k_tE<<<NEDGE / 2, 256, 0, stream>>>(en, emask, cnt, out2, tE);
    k_tail<<<NODES / MT, 256, 0, stream>>>(out2, tE, cnt, elist2, alpha, bg, fgw,
                                           attO, attg, opw, opb, out);
}